// Round 11
// baseline (312.317 us; speedup 1.0000x reference)
//
#include <hip/hip_runtime.h>
#include <hip/hip_bf16.h>

// Causal SDPA, B=4 H=16 S=2048 D=128, fp32 in/out, bf16 MFMA compute.
// R10: SINGLE-KERNEL. Post-mortem of R4/R7/R9: (total - fa_fwd) is a
// CONSTANT ~171us = conv_bf16 + trans_v + launch overhead — bigger than
// fa_fwd itself. Both pre-kernels eliminated:
//  - K staged from fp32 with v_cvt_pk_bf16_f32 at staging time.
//  - V staged ROW-major [key][d] (coalesced fp32 loads, no transpose
//    kernel) into [key/4][d/16][4][16]-blocked LDS (block stride 648
//    shorts, +8 pad -> 2-way banks); PV B-frags read via
//    ds_read_b64_tr_b16 (HW transpose): lane(q,l16) base =
//    1296*(8kc+2q)+160*dt+8*l16, second read offset:1296 -> delivers
//    V[32kc+8q+j][16dt+l16] j=0..7 ascending == R9's vf exactly.
//    Counted lgkmcnt + sched_barrier(0) per rule-18; 1-deep dt pipeline.
// fa_fwd core otherwise identical to measured R9 (126us, 124 VGPR):
// dbuf 1-barrier, balanced pairing {b,1023-b}=34 tiles, swapped QK^T,
// in-reg P via cvt_pk+permlane, fixed-max exp2 softmax, setprio.

#define SEQ 2048
#define DIM 128
#define BM 128                 // per block (4 waves x 32 rows)
#define BN 64
#define BHN 64
#define NTILES 1024            // 16 qtiles x 64 bh
#define KSTRIDE (DIM + 8)      // 136 shorts
#define VKG 648                // V key-group stride in shorts (8 blk x 80 + 8)
#define VDB 80                 // V d-block stride in shorts (64 + 16 pad)
#define M_FIXED 14.0f          // fixed softmax max in exp2 domain

typedef short bf16x8 __attribute__((ext_vector_type(8)));
typedef short s16x4 __attribute__((ext_vector_type(4)));
typedef float f32x4 __attribute__((ext_vector_type(4)));

__device__ __forceinline__ short f2bf(float f) {
  union { float f; unsigned u; } v; v.f = f;
  return (short)((v.u + 0x8000u) >> 16);
}
__device__ __forceinline__ unsigned cvt_pk(float lo, float hi) {
  unsigned r;
  asm("v_cvt_pk_bf16_f32 %0, %1, %2" : "=v"(r) : "v"(lo), "v"(hi));
  return r;
}
__device__ __forceinline__ bf16x8 conv8(float4 a, float4 b) {
  union { unsigned u[4]; bf16x8 v; } r;
  r.u[0] = cvt_pk(a.x, a.y); r.u[1] = cvt_pk(a.z, a.w);
  r.u[2] = cvt_pk(b.x, b.y); r.u[3] = cvt_pk(b.z, b.w);
  return r.v;
}

__global__ __launch_bounds__(256, 2)
void fa_fwd(const float* __restrict__ Qg, const float* __restrict__ Kg,
            const float* __restrict__ Vg, float* __restrict__ Og) {
  __shared__ short ksh[2][BN * KSTRIDE];   // 2 x 17,408 B  [key][d]
  __shared__ short vsh[2][16 * VKG];       // 2 x 20,736 B  blocked for tr

  const int tid   = threadIdx.x;
  const int wave  = tid >> 6;
  const int lane  = tid & 63;
  const int quad  = lane >> 4;
  const int l16   = lane & 15;
  const float SCL = 0.08838834764831845f * 1.4426950408889634f;

  // staging index precompute: 4 chunks of 8 elems per thread (256 threads)
  int krow[4], kcol[4], vwadr[4];
  #pragma unroll
  for (int it = 0; it < 4; ++it) {
    int idx = it * 2048 + tid * 8;
    krow[it] = idx >> 7; kcol[it] = idx & 127;
    vwadr[it] = (krow[it] >> 2) * VKG + (kcol[it] >> 4) * VDB
              + (krow[it] & 3) * 16 + (kcol[it] & 15);
  }

  // per-lane byte base (within a vsh buffer) for tr reads, minus kc/dt terms
  const unsigned trbase = 2592u * quad + 8u * l16;

  #pragma unroll 1
  for (int round = 0; round < 2; ++round) {
    const int item = round == 0 ? (int)blockIdx.x : (NTILES - 1 - (int)blockIdx.x);
    const int qtile = 15 - (item >> 6);
    const int bh    = item & 63;
    const int qw = qtile * BM + wave * 32;   // this wave's 32 q-rows
    const size_t base = (size_t)bh * SEQ * DIM;
    const int ntiles = 2 * qtile + 2;        // >= 2 always

    // ---- Q fragments for both 16-row sub-tiles ----
    bf16x8 qf[2][4];
    #pragma unroll
    for (int s = 0; s < 2; ++s) {
      const float* qp = Qg + base + (size_t)(qw + s * 16 + l16) * DIM + quad * 8;
      #pragma unroll
      for (int kc = 0; kc < 4; ++kc) {
        float4 a = ((const float4*)(qp + kc * 32))[0];
        float4 b = ((const float4*)(qp + kc * 32))[1];
        bf16x8 f;
        f[0] = f2bf(a.x * SCL); f[1] = f2bf(a.y * SCL);
        f[2] = f2bf(a.z * SCL); f[3] = f2bf(a.w * SCL);
        f[4] = f2bf(b.x * SCL); f[5] = f2bf(b.y * SCL);
        f[6] = f2bf(b.z * SCL); f[7] = f2bf(b.w * SCL);
        qf[s][kc] = f;
      }
    }

    f32x4 oacc[2][8];
    #pragma unroll
    for (int s = 0; s < 2; ++s)
      #pragma unroll
      for (int i = 0; i < 8; ++i) oacc[s][i] = (f32x4){0.f, 0.f, 0.f, 0.f};
    float l_run[2] = {0.f, 0.f};

    const float* gK = Kg + base;
    const float* gV = Vg + base;
    float4 kpa[4], kpb[4], vpa[4], vpb[4];   // fp32 prefetch (next tile)

    // ---- prologue: tile 0 -> buf0 (convert inline); tile 1 -> regs ----
    #pragma unroll
    for (int it = 0; it < 4; ++it) {
      const float4* kp = (const float4*)(gK + (size_t)krow[it] * DIM + kcol[it]);
      *(bf16x8*)&ksh[0][krow[it] * KSTRIDE + kcol[it]] = conv8(kp[0], kp[1]);
      const float4* vp = (const float4*)(gV + (size_t)krow[it] * DIM + kcol[it]);
      *(bf16x8*)&vsh[0][vwadr[it]] = conv8(vp[0], vp[1]);
    }
    #pragma unroll
    for (int it = 0; it < 4; ++it) {
      const float4* kp = (const float4*)(gK + (size_t)(BN + krow[it]) * DIM + kcol[it]);
      kpa[it] = kp[0]; kpb[it] = kp[1];
      const float4* vp = (const float4*)(gV + (size_t)(BN + krow[it]) * DIM + kcol[it]);
      vpa[it] = vp[0]; vpb[it] = vp[1];
    }
    __syncthreads();

    for (int kt = 0; kt < ntiles; ++kt) {
      const int kb = kt * BN;
      const int cur = kt & 1;
      const bool act = (kb <= qw + 31);

      // ---- QK^T swapped: mfma(K, Q) -> lane holds P^T[key][q=l16] ----
      f32x4 sc[2][4];
      if (act) {
        #pragma unroll
        for (int s = 0; s < 2; ++s)
          #pragma unroll
          for (int t = 0; t < 4; ++t)
            sc[s][t] = (f32x4){-M_FIXED, -M_FIXED, -M_FIXED, -M_FIXED};

        __builtin_amdgcn_s_setprio(1);
        #pragma unroll
        for (int t = 0; t < 4; ++t) {
          #pragma unroll
          for (int kc = 0; kc < 4; ++kc) {
            bf16x8 kf = *(const bf16x8*)&ksh[cur][(t * 16 + l16) * KSTRIDE + kc * 32 + quad * 8];
            sc[0][t] = __builtin_amdgcn_mfma_f32_16x16x32_bf16(kf, qf[0][kc], sc[0][t], 0, 0, 0);
            sc[1][t] = __builtin_amdgcn_mfma_f32_16x16x32_bf16(kf, qf[1][kc], sc[1][t], 0, 0, 0);
          }
        }
        __builtin_amdgcn_s_setprio(0);
      }

      // ---- stage tile kt+1 (convert fp32 regs -> bf16 LDS), then issue
      //      fp32 loads for tile kt+2 ----
      if (kt + 1 < ntiles) {
        #pragma unroll
        for (int it = 0; it < 4; ++it) {
          *(bf16x8*)&ksh[cur ^ 1][krow[it] * KSTRIDE + kcol[it]] = conv8(kpa[it], kpb[it]);
          *(bf16x8*)&vsh[cur ^ 1][vwadr[it]] = conv8(vpa[it], vpb[it]);
        }
        if (kt + 2 < ntiles) {
          #pragma unroll
          for (int it = 0; it < 4; ++it) {
            const float4* kp = (const float4*)(gK + (size_t)(kb + 2 * BN + krow[it]) * DIM + kcol[it]);
            kpa[it] = kp[0]; kpb[it] = kp[1];
            const float4* vp = (const float4*)(gV + (size_t)(kb + 2 * BN + krow[it]) * DIM + kcol[it]);
            vpa[it] = vp[0]; vpb[it] = vp[1];
          }
        }
      }

      if (act) {
        // ---- fixed-max softmax (exp2 domain); bias already in sc ----
        #pragma unroll
        for (int s = 0; s < 2; ++s) {
          const int qs = qw + s * 16;
          if (kb + 63 <= qs) {
            #pragma unroll
            for (int t = 0; t < 4; ++t)
              #pragma unroll
              for (int r = 0; r < 4; ++r)
                sc[s][t][r] = exp2f(sc[s][t][r]);
          } else {
            const int qrow = qs + l16;
            #pragma unroll
            for (int t = 0; t < 4; ++t) {
              #pragma unroll
              for (int r = 0; r < 4; ++r) {
                int key = kb + t * 16 + quad * 4 + r;
                sc[s][t][r] = (key <= qrow) ? exp2f(sc[s][t][r]) : 0.f;
              }
            }
          }
          l_run[s] += (((sc[s][0][0] + sc[s][0][1]) + (sc[s][0][2] + sc[s][0][3]))
                     + ((sc[s][1][0] + sc[s][1][1]) + (sc[s][1][2] + sc[s][1][3])))
                    + (((sc[s][2][0] + sc[s][2][1]) + (sc[s][2][2] + sc[s][2][3]))
                     + ((sc[s][3][0] + sc[s][3][1]) + (sc[s][3][2] + sc[s][3][3])));
        }

        // ---- build PV A-frags fully in-register (cvt_pk + permlane) ----
        bf16x8 pfrag[2][2];
        #pragma unroll
        for (int s = 0; s < 2; ++s) {
          #pragma unroll
          for (int kc = 0; kc < 2; ++kc) {
            unsigned alo = cvt_pk(sc[s][2 * kc][0],     sc[s][2 * kc][1]);
            unsigned blo = cvt_pk(sc[s][2 * kc][2],     sc[s][2 * kc][3]);
            unsigned ahi = cvt_pk(sc[s][2 * kc + 1][0], sc[s][2 * kc + 1][1]);
            unsigned bhi = cvt_pk(sc[s][2 * kc + 1][2], sc[s][2 * kc + 1][3]);
            auto xy  = __builtin_amdgcn_permlane32_swap(alo, ahi, false, false);
            auto w02 = __builtin_amdgcn_permlane16_swap(xy[0], xy[1], false, false);
            auto xy2 = __builtin_amdgcn_permlane32_swap(blo, bhi, false, false);
            auto w13 = __builtin_amdgcn_permlane16_swap(xy2[0], xy2[1], false, false);
            union { unsigned u[4]; bf16x8 v; } pu;
            pu.u[0] = w02[0]; pu.u[1] = w13[0];
            pu.u[2] = w02[1]; pu.u[3] = w13[1];
            pfrag[s][kc] = pu.v;
          }
        }

        // ---- PV: B-frags via ds_read_b64_tr_b16, 1-deep dt pipeline ----
        const unsigned vb = (unsigned)(size_t)(&vsh[cur][0]) + trbase;
        s16x4 tA[2][2], tB[2][2];          // [stage][kc]
        __builtin_amdgcn_s_setprio(1);
        #pragma unroll
        for (int kc = 0; kc < 2; ++kc) {
          unsigned va = vb + 10368u * kc;  // dt = 0
          asm volatile("ds_read_b64_tr_b16 %0, %2\n\t"
                       "ds_read_b64_tr_b16 %1, %2 offset:1296"
                       : "=&v"(tA[0][kc]), "=&v"(tB[0][kc]) : "v"(va));
        }
        #pragma unroll
        for (int dt = 0; dt < 8; ++dt) {
          const int st = dt & 1;
          if (dt < 7) {
            #pragma unroll
            for (int kc = 0; kc < 2; ++kc) {
              unsigned va = vb + 10368u * kc + 160u * (dt + 1);
              asm volatile("ds_read_b64_tr_b16 %0, %2\n\t"
                           "ds_read_b64_tr_b16 %1, %2 offset:1296"
                           : "=&v"(tA[st ^ 1][kc]), "=&v"(tB[st ^ 1][kc]) : "v"(va));
            }
            asm volatile("s_waitcnt lgkmcnt(4)" ::: "memory");
          } else {
            asm volatile("s_waitcnt lgkmcnt(0)" ::: "memory");
          }
          __builtin_amdgcn_sched_barrier(0);
          #pragma unroll
          for (int kc = 0; kc < 2; ++kc) {
            union { struct { s16x4 a, b; } s; bf16x8 v; } u;
            u.s.a = tA[st][kc]; u.s.b = tB[st][kc];
            oacc[0][dt] = __builtin_amdgcn_mfma_f32_16x16x32_bf16(pfrag[0][kc], u.v, oacc[0][dt], 0, 0, 0);
            oacc[1][dt] = __builtin_amdgcn_mfma_f32_16x16x32_bf16(pfrag[1][kc], u.v, oacc[1][dt], 0, 0, 0);
          }
        }
        __builtin_amdgcn_s_setprio(0);
      }

      // one barrier per tile (dbuf): fences buf[cur] reads from next
      // iter's writes and buf[cur^1] writes from next iter's reads.
      __syncthreads();
    }

    // ---- epilogue ----
    #pragma unroll
    for (int s = 0; s < 2; ++s) {
      l_run[s] += __shfl_xor(l_run[s], 16, 64);
      l_run[s] += __shfl_xor(l_run[s], 32, 64);
    }

    #pragma unroll
    for (int s = 0; s < 2; ++s)
      #pragma unroll
      for (int r = 0; r < 4; ++r) {
        float inv = 1.0f / __shfl(l_run[s], quad * 4 + r, 64);
        float* op = Og + base + (size_t)(qw + s * 16 + quad * 4 + r) * DIM + l16;
        #pragma unroll
        for (int dt = 0; dt < 8; ++dt) op[dt * 16] = oacc[s][dt][r] * inv;
      }
  }
}

extern "C" void kernel_launch(void* const* d_in, const int* in_sizes, int n_in,
                              void* d_out, int out_size, void* d_ws, size_t ws_size,
                              hipStream_t stream) {
  const float* Q = (const float*)d_in[0];
  const float* K = (const float*)d_in[1];
  const float* V = (const float*)d_in[2];
  float* O = (float*)d_out;
  fa_fwd<<<NTILES / 2, 256, 0, stream>>>(Q, K, V, O);
}